// Round 2
// baseline (262.173 us; speedup 1.0000x reference)
//
#include <hip/hip_runtime.h>
#include <hip/hip_bf16.h>

#define Bsz   512
#define Tlen  1024
#define Ktag  48
#define NREAL 45          // tags 0..44 are real; 45=START, 46=STOP, 47=PAD
#define HALF_T 512
#define STOPT 46
#define NEGV  -10000.0f
#define GB    16          // batch columns per wave (MFMA N) on the MFMA path

typedef float          f32x4  __attribute__((ext_vector_type(4)));
typedef short          bf16x4 __attribute__((ext_vector_type(4)));
typedef unsigned short u16x4  __attribute__((ext_vector_type(4)));

#if defined(__has_builtin)
#  if __has_builtin(__builtin_amdgcn_mfma_f32_16x16x16bf16_1k)
#    define HAVE_MFMA16 1
#  endif
#endif
#ifndef HAVE_MFMA16
#  define HAVE_MFMA16 0
#endif

// ---------------------------------------------------------------------------
// Two execution paths, selected by an in-kernel MFMA layout probe:
//  - MFMA panel path: 16 chains/wave, one 48x48 x 48x16 step via 16x16x16
//    bf16 MFMAs (split hi/lo transition matrix). Requires the D->B feed
//    identity (B-frag k = 4*(lane>>4)+j, col = lane&15 == verified D-frag
//    row/col map). The probe DISCOVERS the A-map and VALIDATES the B-map
//    with exact small-int matrices before committing.
//  - VALU fallback: the proven per-lane broadcast kernel (round-0).
// ---------------------------------------------------------------------------

__device__ __forceinline__ float wave_max(float v) {
#pragma unroll
    for (int off = 32; off > 0; off >>= 1)
        v = fmaxf(v, __shfl_xor(v, off, 64));
    return v;
}
__device__ __forceinline__ float wave_sum(float v) {
#pragma unroll
    for (int off = 32; off > 0; off >>= 1)
        v += __shfl_xor(v, off, 64);
    return v;
}
__device__ __forceinline__ float bcast(float v, int l) {
    return __int_as_float(__builtin_amdgcn_readlane(__float_as_int(v), l));
}

template <bool BF16>
__device__ __forceinline__ float ld(const void* p, size_t i) {
    if constexpr (BF16) {
        unsigned int u = ((const unsigned short*)p)[i];
        return __uint_as_float(u << 16);
    } else {
        return ((const float*)p)[i];
    }
}

__device__ __forceinline__ unsigned pk2(float lo, float hi) {
    unsigned r;
    asm("v_cvt_pk_bf16_f32 %0, %1, %2" : "=v"(r) : "v"(lo), "v"(hi));
    return r;
}
__device__ __forceinline__ bf16x4 mk4(unsigned a, unsigned b) {
    union { unsigned u[2]; bf16x4 v; } c; c.u[0] = a; c.u[1] = b; return c.v;
}

template <bool BF16> struct EmT { using T = f32x4; };
template <>          struct EmT<true> { using T = u16x4; };

__device__ __forceinline__ f32x4 tof4(f32x4 v) { return v; }
__device__ __forceinline__ f32x4 tof4(u16x4 v) {
    f32x4 r;
    r.x = __uint_as_float((unsigned)v.x << 16);
    r.y = __uint_as_float((unsigned)v.y << 16);
    r.z = __uint_as_float((unsigned)v.z << 16);
    r.w = __uint_as_float((unsigned)v.w << 16);
    return r;
}

#if HAVE_MFMA16
__device__ __forceinline__ f32x4 mfma16(bf16x4 a, bf16x4 b, f32x4 c) {
    return __builtin_amdgcn_mfma_f32_16x16x16bf16_1k(a, b, c, 0, 0, 0);
}

__device__ __forceinline__ bf16x4 pk4(f32x4 u) {
    return mk4(pk2(u.x, u.y), pk2(u.z, u.w));
}
__device__ __forceinline__ bf16x4 pkmul(f32x4 u, f32x4 e) {
    return mk4(pk2(u.x * __expf(e.x), u.y * __expf(e.y)),
               pk2(u.z * __expf(e.z), u.w * __expf(e.w)));
}
__device__ __forceinline__ f32x4 mulexp(f32x4 a, f32x4 e) {
    f32x4 r;
    r.x = a.x * __expf(e.x); r.y = a.y * __expf(e.y);
    r.z = a.z * __expf(e.z); r.w = a.w * __expf(e.w);
    return r;
}
__device__ __forceinline__ f32x4 sel4(bool a, f32x4 x, f32x4 y) {
    f32x4 r;
    r.x = a ? x.x : y.x; r.y = a ? x.y : y.y;
    r.z = a ? x.z : y.z; r.w = a ? x.w : y.w;
    return r;
}

// ---- layout probe: exact small-int matrices, two independent trials ----
__device__ __forceinline__ int Ft1(int i, int k) { return ((3*i + 5*k) % 7) - 3; }
__device__ __forceinline__ int Gt1(int k, int c) { return ((2*k + 3*c) % 5) - 2; }
__device__ __forceinline__ int Ft2(int i, int k) { return ((5*i + 7*k) % 11) - 5; }
__device__ __forceinline__ int Gt2(int k, int c) { return ((3*k + 2*c) % 9) - 4; }

// returns av*3+bv of the validated layout combo, or -1.
// av/bv: 0 -> (row/col=lane&15, k=4*(lane>>4)+j)   [feed-compatible B]
//        1 -> (row/col=lane&15, k=(lane>>4)+4*j)
//        2 -> transposed (k=lane&15, row/col=4*(lane>>4)+j)
// D is read through the verified map: col=lane&15, row=4*(lane>>4)+reg.
__device__ int probe_layout() {
    const int lane = threadIdx.x & 63;
    const int b = lane & 15, g = lane >> 4;
    float e1[4], e2[4];
#pragma unroll
    for (int r = 0; r < 4; r++) {
        int s1 = 0, s2 = 0;
        for (int k = 0; k < 16; k++) {
            s1 += Ft1(4*g + r, k) * Gt1(k, b);
            s2 += Ft2(4*g + r, k) * Gt2(k, b);
        }
        e1[r] = (float)s1; e2[r] = (float)s2;
    }
    int found = -1;
    for (int av = 0; av < 3; av++) {
        for (int bv = 0; bv < 3; bv++) {
            float A1[4], B1[4], A2[4], B2[4];
#pragma unroll
            for (int j = 0; j < 4; j++) {
                int ar, ak, bk, bc;
                if (av == 0)      { ar = b;       ak = 4*g + j; }
                else if (av == 1) { ar = b;       ak = g + 4*j; }
                else              { ar = 4*g + j; ak = b;       }
                if (bv == 0)      { bk = 4*g + j; bc = b;       }
                else if (bv == 1) { bk = g + 4*j; bc = b;       }
                else              { bk = b;       bc = 4*g + j; }
                A1[j] = (float)Ft1(ar, ak);  B1[j] = (float)Gt1(bk, bc);
                A2[j] = (float)Ft2(ar, ak);  B2[j] = (float)Gt2(bk, bc);
            }
            f32x4 z = {0.f, 0.f, 0.f, 0.f};
            f32x4 d1 = mfma16(mk4(pk2(A1[0],A1[1]), pk2(A1[2],A1[3])),
                              mk4(pk2(B1[0],B1[1]), pk2(B1[2],B1[3])), z);
            f32x4 d2 = mfma16(mk4(pk2(A2[0],A2[1]), pk2(A2[2],A2[3])),
                              mk4(pk2(B2[0],B2[1]), pk2(B2[2],B2[3])), z);
            bool ok = d1.x==e1[0] && d1.y==e1[1] && d1.z==e1[2] && d1.w==e1[3]
                   && d2.x==e2[0] && d2.y==e2[1] && d2.z==e2[2] && d2.w==e2[3];
            if (__all(ok) && found < 0) found = av*3 + bv;
        }
    }
    return found;
}

// ---- MFMA panel path: 1 wave handles GB=16 chains --------------------------
template <bool BF16>
__device__ void crf_mfma(const void* __restrict__ h, const void* __restrict__ mask,
                         const void* __restrict__ trans, float* __restrict__ ws,
                         int amap, float (*ltr)[Ktag + 1], float* lse) {
    using ET = typename EmT<BF16>::T;
    constexpr size_t esz = BF16 ? 2 : 4;

    const int lane = threadIdx.x;
    const int gw   = blockIdx.x;                 // 0..63
    const bool fwd = gw < (Bsz / GB);
    const int b0   = (fwd ? gw : gw - (Bsz / GB)) * GB;
    const int b    = lane & 15;
    const int g    = lane >> 4;

    for (int idx = lane; idx < Ktag * Ktag; idx += 64)
        ltr[idx / Ktag][idx % Ktag] = ld<BF16>(trans, (size_t)idx);
    __syncthreads();

    if (fwd && lane < Ktag) {
        float mx = -3.0e38f;
        for (int j = 0; j < Ktag; j++)
            mx = fmaxf(mx, ltr[lane][j] + (j == STOPT ? 0.f : NEGV));
        float s = 0.f;
        for (int j = 0; j < Ktag; j++)
            s += __expf(ltr[lane][j] + (j == STOPT ? 0.f : NEGV) - mx);
        lse[lane] = mx + __logf(s);
    }
    __syncthreads();

    // split-bf16 transition fragments; fwd: A=E, bwd: A=E^T; slot map per amap
    bf16x4 Eh[3][3], El[3][3];
#pragma unroll
    for (int m = 0; m < 3; m++) {
#pragma unroll
        for (int c = 0; c < 3; c++) {
            float x[4];
#pragma unroll
            for (int j = 0; j < 4; j++) {
                int rr, kk;
                if (amap == 0)      { rr = b;       kk = 4*g + j; }
                else if (amap == 1) { rr = b;       kk = g + 4*j; }
                else                { rr = 4*g + j; kk = b;       }
                int R = 16*m + rr, K = 16*c + kk;
                x[j] = fwd ? __expf(ltr[R][K]) : __expf(ltr[K][R]);
            }
            unsigned h01 = pk2(x[0], x[1]), h23 = pk2(x[2], x[3]);
            Eh[m][c] = mk4(h01, h23);
            float l0 = x[0] - __uint_as_float(h01 << 16);
            float l1 = x[1] - __uint_as_float(h01 & 0xFFFF0000u);
            float l2 = x[2] - __uint_as_float(h23 << 16);
            float l3 = x[3] - __uint_as_float(h23 & 0xFFFF0000u);
            El[m][c] = mk4(pk2(l0, l1), pk2(l2, l3));
        }
    }

    const char* hb = (const char*)h + ((size_t)(b0 + b) * Tlen * Ktag + 4 * g) * esz;

    float* uF = ws;
    float* MF = ws + (size_t)Bsz * Ktag;
    float* uB = MF + Bsz;
    float* MB = uB + (size_t)Bsz * Ktag;

    f32x4 U[3];
    float M;
    int lenv = 0;

    if (fwd) {
        f32x4 e0[3];
#pragma unroll
        for (int c = 0; c < 3; c++)
            e0[c] = tof4(*(const ET*)(hb + (size_t)(16 * c) * esz));
        float cmax = -3.0e38f;
        float sc[3][4];
#pragma unroll
        for (int c = 0; c < 3; c++)
#pragma unroll
            for (int j = 0; j < 4; j++) {
                int i = 16*c + 4*g + j;
                float v = (i < NREAL) ? (e0[c][j] + lse[i]) : -3.0e38f;
                sc[c][j] = v;
                cmax = fmaxf(cmax, v);
            }
        cmax = fmaxf(cmax, __shfl_xor(cmax, 16, 64));
        cmax = fmaxf(cmax, __shfl_xor(cmax, 32, 64));
        M = cmax;
#pragma unroll
        for (int c = 0; c < 3; c++)
#pragma unroll
            for (int j = 0; j < 4; j++)
                U[c][j] = (16*c + 4*g + j < NREAL) ? __expf(sc[c][j] - cmax) : 0.f;
    } else {
        const char* mb = (const char*)mask + (size_t)(b0 + b) * Tlen * esz;
        float cs = 0.f;
        for (int kk = 0; kk < Tlen / 16; kk++) {
            f32x4 v = tof4(*(const ET*)(mb + (size_t)(kk * 16 + 4 * g) * esz));
            cs += (v.x + v.y) + (v.z + v.w);
        }
        cs += __shfl_xor(cs, 16, 64);
        cs += __shfl_xor(cs, 32, 64);
        lenv = (int)(cs + 0.5f);

        float cmax = -3.0e38f;
        float gv[3][4];
#pragma unroll
        for (int c = 0; c < 3; c++)
#pragma unroll
            for (int j = 0; j < 4; j++) {
                gv[c][j] = ltr[STOPT][16*c + 4*g + j];
                cmax = fmaxf(cmax, gv[c][j]);
            }
        cmax = fmaxf(cmax, __shfl_xor(cmax, 16, 64));
        cmax = fmaxf(cmax, __shfl_xor(cmax, 32, 64));
        M = cmax;
#pragma unroll
        for (int c = 0; c < 3; c++)
#pragma unroll
            for (int j = 0; j < 4; j++)
                U[c][j] = __expf(gv[c][j] - cmax);
    }

    if (fwd) {
        ET em[4][3], emn[4][3];
#pragma unroll
        for (int k = 0; k < 4; k++)
#pragma unroll
            for (int c = 0; c < 3; c++)
                em[k][c] = *(const ET*)(hb + ((size_t)(1 + k) * Ktag + 16*c) * esz);
        for (int t = 1; t < HALF_T; t += 4) {
#pragma unroll
            for (int k = 0; k < 4; k++) {
                int tt = t + 4 + k; if (tt > HALF_T - 1) tt = HALF_T - 1;
#pragma unroll
                for (int c = 0; c < 3; c++)
                    emn[k][c] = *(const ET*)(hb + ((size_t)tt * Ktag + 16*c) * esz);
            }
#pragma unroll
            for (int k = 0; k < 4; k++) {
                if (t + k < HALF_T) {
                    bf16x4 V[3];
#pragma unroll
                    for (int c = 0; c < 3; c++) V[c] = pk4(U[c]);
                    f32x4 a0 = {0.f,0.f,0.f,0.f};
                    f32x4 a1 = {0.f,0.f,0.f,0.f};
                    f32x4 a2 = {0.f,0.f,0.f,0.f};
#pragma unroll
                    for (int c = 0; c < 3; c++) {
                        a0 = mfma16(Eh[0][c], V[c], a0);
                        a1 = mfma16(Eh[1][c], V[c], a1);
                        a2 = mfma16(Eh[2][c], V[c], a2);
                    }
#pragma unroll
                    for (int c = 0; c < 3; c++) {
                        a0 = mfma16(El[0][c], V[c], a0);
                        a1 = mfma16(El[1][c], V[c], a1);
                        a2 = mfma16(El[2][c], V[c], a2);
                    }
                    U[0] = mulexp(a0, tof4(em[k][0]));
                    U[1] = mulexp(a1, tof4(em[k][1]));
                    U[2] = mulexp(a2, tof4(em[k][2]));
                }
            }
            float mx = fmaxf(fmaxf(U[0].x, U[0].y), fmaxf(U[0].z, U[0].w));
            mx = fmaxf(mx, fmaxf(fmaxf(U[1].x, U[1].y), fmaxf(U[1].z, U[1].w)));
            mx = fmaxf(mx, fmaxf(fmaxf(U[2].x, U[2].y), fmaxf(U[2].z, U[2].w)));
            mx = fmaxf(mx, __shfl_xor(mx, 16, 64));
            mx = fmaxf(mx, __shfl_xor(mx, 32, 64));
            float inv = 1.0f / mx;
            U[0] *= inv; U[1] *= inv; U[2] *= inv;
            M += __logf(mx);
#pragma unroll
            for (int k = 0; k < 4; k++)
#pragma unroll
                for (int c = 0; c < 3; c++) em[k][c] = emn[k][c];
        }
#pragma unroll
        for (int c = 0; c < 3; c++)
#pragma unroll
            for (int j = 0; j < 4; j++)
                uF[(size_t)(b0 + b) * Ktag + 16*c + 4*g + j] = U[c][j];
        if (lane < GB) MF[b0 + lane] = M;
    } else {
        ET em[4][3], emn[4][3];
#pragma unroll
        for (int k = 0; k < 4; k++)
#pragma unroll
            for (int c = 0; c < 3; c++)
                em[k][c] = *(const ET*)(hb + ((size_t)(Tlen - 1 - k) * Ktag + 16*c) * esz);
        for (int tg = Tlen - 1; tg >= HALF_T; tg -= 4) {
#pragma unroll
            for (int k = 0; k < 4; k++) {
                int tt = tg - 4 - k; if (tt < HALF_T) tt = HALF_T;
#pragma unroll
                for (int c = 0; c < 3; c++)
                    emn[k][c] = *(const ET*)(hb + ((size_t)tt * Ktag + 16*c) * esz);
            }
#pragma unroll
            for (int k = 0; k < 4; k++) {
                const int t = tg - k;            // (1024-512)%4==0: no tail guard
                const bool act = (t < lenv);
                bf16x4 V[3];
#pragma unroll
                for (int c = 0; c < 3; c++) V[c] = pkmul(U[c], tof4(em[k][c]));
                f32x4 a0 = {0.f,0.f,0.f,0.f};
                f32x4 a1 = {0.f,0.f,0.f,0.f};
                f32x4 a2 = {0.f,0.f,0.f,0.f};
#pragma unroll
                for (int c = 0; c < 3; c++) {
                    a0 = mfma16(Eh[0][c], V[c], a0);
                    a1 = mfma16(Eh[1][c], V[c], a1);
                    a2 = mfma16(Eh[2][c], V[c], a2);
                }
#pragma unroll
                for (int c = 0; c < 3; c++) {
                    a0 = mfma16(El[0][c], V[c], a0);
                    a1 = mfma16(El[1][c], V[c], a1);
                    a2 = mfma16(El[2][c], V[c], a2);
                }
                U[0] = sel4(act, a0, U[0]);
                U[1] = sel4(act, a1, U[1]);
                U[2] = sel4(act, a2, U[2]);
            }
            float mx = fmaxf(fmaxf(U[0].x, U[0].y), fmaxf(U[0].z, U[0].w));
            mx = fmaxf(mx, fmaxf(fmaxf(U[1].x, U[1].y), fmaxf(U[1].z, U[1].w)));
            mx = fmaxf(mx, fmaxf(fmaxf(U[2].x, U[2].y), fmaxf(U[2].z, U[2].w)));
            mx = fmaxf(mx, __shfl_xor(mx, 16, 64));
            mx = fmaxf(mx, __shfl_xor(mx, 32, 64));
            float inv = 1.0f / mx;
            U[0] *= inv; U[1] *= inv; U[2] *= inv;
            M += __logf(mx);
#pragma unroll
            for (int k = 0; k < 4; k++)
#pragma unroll
                for (int c = 0; c < 3; c++) em[k][c] = emn[k][c];
        }
#pragma unroll
        for (int c = 0; c < 3; c++)
#pragma unroll
            for (int j = 0; j < 4; j++)
                uB[(size_t)(b0 + b) * Ktag + 16*c + 4*g + j] = U[c][j];
        if (lane < GB) MB[b0 + lane] = M;
    }
}
#endif  // HAVE_MFMA16

// ---- VALU fallback: verbatim proven round-0 path ---------------------------
template <bool BF16>
__device__ void crf_valu(const void* __restrict__ h, const void* __restrict__ mask,
                         const void* __restrict__ trans, float* __restrict__ ws,
                         float (*ltr)[Ktag + 1]) {
    const int lane = threadIdx.x;
    const int bid  = blockIdx.x;
    const bool fwd = bid < Bsz;
    const int b    = fwd ? bid : bid - Bsz;

    for (int idx = lane; idx < Ktag * Ktag; idx += 64) {
        int i = idx / Ktag;
        ltr[i][idx - i * Ktag] = ld<BF16>(trans, (size_t)idx);
    }
    __syncthreads();

    float E[Ktag];
#pragma unroll
    for (int j = 0; j < Ktag; j++) E[j] = 0.f;
    if (lane < Ktag) {
        if (fwd) {
#pragma unroll
            for (int j = 0; j < Ktag; j++) E[j] = __expf(ltr[lane][j]);
        } else {
#pragma unroll
            for (int i = 0; i < Ktag; i++) E[i] = __expf(ltr[i][lane]);
        }
    }

    const int li = (lane < Ktag) ? lane : (Ktag - 1);
    const size_t hb = (size_t)b * Tlen * Ktag;

    float* uF = ws;
    float* MF = ws + (size_t)Bsz * Ktag;
    float* uB = MF + Bsz;
    float* MB = uB + (size_t)Bsz * Ktag;

    float u = 0.f, M = 0.f;

    if (fwd) {
        {
            float e0 = ld<BF16>(h, hb + li);
            float mx = -3.0e38f;
#pragma unroll
            for (int j = 0; j < Ktag; j++) {
                float v = ltr[li][j] + (j == STOPT ? 0.f : NEGV);
                mx = fmaxf(mx, v);
            }
            float s = 0.f;
#pragma unroll
            for (int j = 0; j < Ktag; j++) {
                float v = ltr[li][j] + (j == STOPT ? 0.f : NEGV);
                s += __expf(v - mx);
            }
            float sc = e0 + mx + __logf(s);
            if (lane >= NREAL) sc = -3.0e38f;
            float m1 = wave_max(sc);
            M = m1;
            u = (lane < NREAL) ? __expf(sc - m1) : 0.f;
        }
        float em[4], emn[4];
#pragma unroll
        for (int k = 0; k < 4; k++) {
            int tt = 1 + k; if (tt > HALF_T - 1) tt = HALF_T - 1;
            em[k] = ld<BF16>(h, hb + (size_t)tt * Ktag + li);
        }
        for (int t = 1; t < HALF_T; t += 4) {
#pragma unroll
            for (int k = 0; k < 4; k++) {
                int tt = t + 4 + k; if (tt > HALF_T - 1) tt = HALF_T - 1;
                emn[k] = ld<BF16>(h, hb + (size_t)tt * Ktag + li);
            }
#pragma unroll
            for (int k = 0; k < 4; k++) {
                if (t + k < HALF_T) {
                    float ee = __expf(em[k]);
                    float a0 = 0.f, a1 = 0.f, a2 = 0.f, a3 = 0.f;
#pragma unroll
                    for (int j = 0; j < Ktag; j += 4) {
                        a0 = fmaf(E[j + 0], bcast(u, j + 0), a0);
                        a1 = fmaf(E[j + 1], bcast(u, j + 1), a1);
                        a2 = fmaf(E[j + 2], bcast(u, j + 2), a2);
                        a3 = fmaf(E[j + 3], bcast(u, j + 3), a3);
                    }
                    u = ((a0 + a1) + (a2 + a3)) * ee;
                }
            }
            float m = wave_max(u);
            u *= 1.0f / m;
            M += __logf(m);
#pragma unroll
            for (int k = 0; k < 4; k++) em[k] = emn[k];
        }
        if (lane < Ktag) uF[(size_t)b * Ktag + lane] = u;
        if (lane == 0) MF[b] = M;
    } else {
        float c = 0.f;
        for (int t0 = lane; t0 < Tlen; t0 += 64)
            c += ld<BF16>(mask, (size_t)b * Tlen + t0);
        c = wave_sum(c);
        int len = (int)(c + 0.5f);

        float g = (lane < Ktag) ? ltr[STOPT][lane] : -3.0e38f;
        float m0 = wave_max(g);
        M = m0;
        u = (lane < Ktag) ? __expf(g - m0) : 0.f;

        int t0 = len - 1;
        float em[4], emn[4];
#pragma unroll
        for (int k = 0; k < 4; k++) {
            int tt = t0 - k; if (tt < HALF_T) tt = HALF_T;
            em[k] = ld<BF16>(h, hb + (size_t)tt * Ktag + li);
        }
        for (int tg = t0; tg >= HALF_T; tg -= 4) {
#pragma unroll
            for (int k = 0; k < 4; k++) {
                int tt = tg - 4 - k; if (tt < HALF_T) tt = HALF_T;
                emn[k] = ld<BF16>(h, hb + (size_t)tt * Ktag + li);
            }
#pragma unroll
            for (int k = 0; k < 4; k++) {
                if (tg - k >= HALF_T) {
                    float ee = __expf(em[k]);
                    float v = u * ee;
                    float a0 = 0.f, a1 = 0.f, a2 = 0.f, a3 = 0.f;
#pragma unroll
                    for (int j = 0; j < Ktag; j += 4) {
                        a0 = fmaf(E[j + 0], bcast(v, j + 0), a0);
                        a1 = fmaf(E[j + 1], bcast(v, j + 1), a1);
                        a2 = fmaf(E[j + 2], bcast(v, j + 2), a2);
                        a3 = fmaf(E[j + 3], bcast(v, j + 3), a3);
                    }
                    u = (a0 + a1) + (a2 + a3);
                }
            }
            float m = wave_max(u);
            u *= 1.0f / m;
            M += __logf(m);
#pragma unroll
            for (int k = 0; k < 4; k++) em[k] = emn[k];
        }
        if (lane < Ktag) uB[(size_t)b * Ktag + lane] = u;
        if (lane == 0) MB[b] = M;
    }
}

__global__ void __launch_bounds__(64) crf_main(const void* __restrict__ h,
                                               const void* __restrict__ mask,
                                               const void* __restrict__ trans,
                                               float* __restrict__ ws) {
    __shared__ float ltr_s[Ktag][Ktag + 1];
#if HAVE_MFMA16
    __shared__ float lse_s[Ktag];
#endif
    bool isbf16 = (((const unsigned short*)mask)[0] == 0x3F80);
#if HAVE_MFMA16
    int lay = probe_layout();
    if (lay >= 0 && (lay % 3) == 0) {       // B-map is feed-compatible
        if (blockIdx.x >= (2 * Bsz) / GB) return;   // 64 worker waves
        int amap = lay / 3;
        if (isbf16) crf_mfma<true >(h, mask, trans, ws, amap, ltr_s, lse_s);
        else        crf_mfma<false>(h, mask, trans, ws, amap, ltr_s, lse_s);
        return;
    }
#endif
    if (isbf16) crf_valu<true >(h, mask, trans, ws, ltr_s);
    else        crf_valu<false>(h, mask, trans, ws, ltr_s);
}

__global__ void __launch_bounds__(64) crf_combine(const void* __restrict__ mask,
                                                  const float* __restrict__ ws,
                                                  void* __restrict__ out) {
    const int b = blockIdx.x;
    const int lane = threadIdx.x;
    const float* uF = ws;
    const float* MF = ws + (size_t)Bsz * Ktag;
    const float* uB = MF + Bsz;
    const float* MB = uB + (size_t)Bsz * Ktag;

    float p = (lane < Ktag) ? uF[(size_t)b * Ktag + lane] * uB[(size_t)b * Ktag + lane] : 0.f;
    float s = wave_sum(p);
    float ans = MF[b] + MB[b] + __logf(s);

    bool isbf16 = (((const unsigned short*)mask)[0] == 0x3F80);
    if (lane == 0) {
        if (isbf16) {
            unsigned int x = __float_as_uint(ans);
            unsigned int r = (x + 0x7FFFu + ((x >> 16) & 1u)) >> 16;  // RNE to bf16
            ((unsigned short*)out)[b] = (unsigned short)r;
        } else {
            ((float*)out)[b] = ans;
        }
    }
}

extern "C" void kernel_launch(void* const* d_in, const int* in_sizes, int n_in,
                              void* d_out, int out_size, void* d_ws, size_t ws_size,
                              hipStream_t stream) {
    const void* h     = d_in[0];  // (B,T,K)
    const void* mask  = d_in[1];  // (B,T)
    const void* trans = d_in[2];  // (K,K)
    float* ws = (float*)d_ws;     // 2*(B*K + B) floats ~= 200 KB

    hipLaunchKernelGGL(crf_main, dim3(2 * Bsz), dim3(64), 0, stream, h, mask, trans, ws);
    hipLaunchKernelGGL(crf_combine, dim3(Bsz), dim3(64), 0, stream, mask, ws, d_out);
}